// Round 1
// baseline (395.769 us; speedup 1.0000x reference)
//
#include <hip/hip_runtime.h>

// ---------------------------------------------------------------------------
// Attention_20117626815094: c_t = softmax(enc @ dec^T, axis=t)^T-contract @ enc
//   B=8, S_ENC=2048, S_DEC=2048, D=1024, fp32 in/out.
// Pipeline (all f16 compute via MFMA 16x16x32_f16, fp32 accumulate):
//   1. conv_enc:  enc fp32 -> enc_h [e][d] f16 AND enc_hT [d][e] f16
//   2. conv_dec:  dec fp32 -> dec_h [t][d] f16
//   3. gemm1:     S_h[e][t] = enc_h @ dec_h^T      (m97 pattern, f16 out)
//   4. row_stats: per (b,e) row: m = max_t S, rl = 1/sum exp(S-m)
//   5. norm_T:    PT[t][e] = exp(S[e][t]-m_e)*rl_e (tiled transpose, f16)
//   6. gemm2:     out[t][d] = PT @ enc_hT^T-form   (m97 pattern, fp32 out)
// Workspace layout (bytes):
//   [0,          33554432)  enc_h   -- reused by PT after gemm1
//   [33554432,   67108864)  dec_h   -- reused by PT after gemm1
//   [67108864,  100663296)  enc_hT
//   [100663296, 167772160)  S_h
//   [167772160, 167903232)  stats (float2 per row)
// ---------------------------------------------------------------------------

typedef _Float16 half8 __attribute__((ext_vector_type(8)));
typedef _Float16 half4v __attribute__((ext_vector_type(4)));
typedef float floatx4 __attribute__((ext_vector_type(4)));

#define BM 128
#define BN 128
#define BK 32

__device__ __forceinline__ void async_load16(const _Float16* g, void* l) {
  __builtin_amdgcn_global_load_lds(
      (const __attribute__((address_space(1))) void*)g,
      (__attribute__((address_space(3))) void*)l, 16, 0, 0);
}

// ---- GEMM: C[m][n] = sum_k A[m][k] * Bt[n][k]; A,Bt row-major f16 ---------
template <typename OutT>
__global__ __launch_bounds__(256, 2) void gemm_bt(
    const _Float16* __restrict__ A, const _Float16* __restrict__ Bt,
    OutT* __restrict__ C, int K, long strideA, long strideB, long strideC,
    int ldA, int ldB, int ldC) {
  __shared__ _Float16 lds_a[BM * BK];
  __shared__ _Float16 lds_b[BN * BK];

  const int b = blockIdx.z;
  A += (long)b * strideA;
  Bt += (long)b * strideB;
  C += (long)b * strideC;
  const int m0 = blockIdx.y * BM;
  const int n0 = blockIdx.x * BN;
  const int tid = threadIdx.x;
  const int lane = tid & 63;
  const int wave = tid >> 6;
  const int quad = lane >> 4;
  const int l16 = lane & 15;
  const int wm = (wave >> 1) * 64;
  const int wn = (wave & 1) * 64;

  floatx4 acc[4][4] = {};

  for (int k0 = 0; k0 < K; k0 += BK) {
    // stage A (8KB) and B (8KB) tiles: 2 chunks x 16B per thread each
#pragma unroll
    for (int c = 0; c < 2; ++c) {
      const int off = c * 4096 + wave * 1024 + lane * 16;  // bytes in tile
      const int row = off >> 6;                            // 64B per row (32 f16)
      const int ke = (off & 63) >> 1;                      // f16 elems in row
      async_load16(A + (long)(m0 + row) * ldA + k0 + ke, (char*)lds_a + off);
      async_load16(Bt + (long)(n0 + row) * ldB + k0 + ke, (char*)lds_b + off);
    }
    __syncthreads();

    half8 af[4], bf[4];
#pragma unroll
    for (int i = 0; i < 4; ++i) {
      af[i] = *(const half8*)&lds_a[(wm + i * 16 + l16) * BK + quad * 8];
      bf[i] = *(const half8*)&lds_b[(wn + i * 16 + l16) * BK + quad * 8];
    }
#pragma unroll
    for (int i = 0; i < 4; ++i)
#pragma unroll
      for (int j = 0; j < 4; ++j)
        acc[i][j] = __builtin_amdgcn_mfma_f32_16x16x32_f16(af[i], bf[j],
                                                           acc[i][j], 0, 0, 0);
    __syncthreads();
  }

  // epilogue: C/D layout col=lane&15, row=quad*4+reg (measured, m89/m91)
#pragma unroll
  for (int i = 0; i < 4; ++i) {
    const int r0 = m0 + wm + i * 16 + quad * 4;
#pragma unroll
    for (int j = 0; j < 4; ++j) {
      const int col = n0 + wn + j * 16 + l16;
#pragma unroll
      for (int r = 0; r < 4; ++r)
        C[(long)(r0 + r) * ldC + col] = (OutT)acc[i][j][r];
    }
  }
}

// ---- enc convert + transpose ----------------------------------------------
__global__ __launch_bounds__(256) void conv_enc(const float* __restrict__ E,
                                                _Float16* __restrict__ Eh,
                                                _Float16* __restrict__ EhT,
                                                int Se, int D) {
  __shared__ _Float16 tile[64][72];  // [d_local][e_local], padded
  const int b = blockIdx.z;
  const int d0 = blockIdx.x * 64;
  const int e0 = blockIdx.y * 64;
  const float* Eb = E + (size_t)b * Se * D;
  _Float16* Ehb = Eh + (size_t)b * Se * D;
  _Float16* EhTb = EhT + (size_t)b * D * Se;
  const int tid = threadIdx.x;
  const int lr = tid >> 4;
  const int lc = (tid & 15) * 4;
#pragma unroll
  for (int r = 0; r < 4; ++r) {
    const int e = e0 + lr + r * 16;
    float4 v = *(const float4*)(Eb + (size_t)e * D + d0 + lc);
    half4v h;
    h[0] = (_Float16)v.x; h[1] = (_Float16)v.y;
    h[2] = (_Float16)v.z; h[3] = (_Float16)v.w;
    *(half4v*)(Ehb + (size_t)e * D + d0 + lc) = h;
#pragma unroll
    for (int j = 0; j < 4; ++j) tile[lc + j][lr + r * 16] = h[j];
  }
  __syncthreads();
#pragma unroll
  for (int r = 0; r < 4; ++r) {
    const int d = lr + r * 16;
    half4v w;
#pragma unroll
    for (int j = 0; j < 4; ++j) w[j] = tile[d][lc + j];
    *(half4v*)(EhTb + (size_t)(d0 + d) * Se + e0 + lc) = w;
  }
}

// ---- dec convert ----------------------------------------------------------
__global__ __launch_bounds__(256) void conv_dec(const float* __restrict__ X,
                                                _Float16* __restrict__ Y) {
  const size_t i = ((size_t)blockIdx.x * 256 + threadIdx.x) * 4;
  float4 v = *(const float4*)(X + i);
  half4v h;
  h[0] = (_Float16)v.x; h[1] = (_Float16)v.y;
  h[2] = (_Float16)v.z; h[3] = (_Float16)v.w;
  *(half4v*)(Y + i) = h;
}

// ---- per-row softmax stats ------------------------------------------------
__global__ __launch_bounds__(256) void row_stats(const _Float16* __restrict__ S,
                                                 float2* __restrict__ stats) {
  __shared__ float red[8];
  const long row = blockIdx.x;
  const _Float16* p = S + row * 2048;
  const int tid = threadIdx.x;
  const int wave = tid >> 6, lane = tid & 63;

  half8 v = *(const half8*)(p + tid * 8);
  float f[8];
#pragma unroll
  for (int j = 0; j < 8; ++j) f[j] = (float)v[j];

  float mx = f[0];
#pragma unroll
  for (int j = 1; j < 8; ++j) mx = fmaxf(mx, f[j]);
  for (int o = 32; o; o >>= 1) mx = fmaxf(mx, __shfl_xor(mx, o, 64));
  if (lane == 0) red[wave] = mx;
  __syncthreads();
  if (tid == 0)
    red[4] = fmaxf(fmaxf(red[0], red[1]), fmaxf(red[2], red[3]));
  __syncthreads();
  mx = red[4];

  float s = 0.f;
#pragma unroll
  for (int j = 0; j < 8; ++j) s += __expf(f[j] - mx);
  for (int o = 32; o; o >>= 1) s += __shfl_xor(s, o, 64);
  if (lane == 0) red[wave] = s;
  __syncthreads();
  if (tid == 0) {
    const float tot = red[0] + red[1] + red[2] + red[3];
    stats[row] = make_float2(mx, 1.0f / tot);
  }
}

// ---- normalize + transpose: PT[t][e] = exp(S[e][t]-m_e)*rl_e --------------
__global__ __launch_bounds__(256) void norm_transpose(
    const _Float16* __restrict__ S, const float2* __restrict__ stats,
    _Float16* __restrict__ PT, int Se, int St) {
  __shared__ _Float16 tile[64][72];  // [t_local][e_local]
  const int b = blockIdx.z;
  const int t0 = blockIdx.x * 64;
  const int e0 = blockIdx.y * 64;
  const _Float16* Sb = S + (size_t)b * Se * St;
  _Float16* Pb = PT + (size_t)b * St * Se;
  const float2* stb = stats + (size_t)b * Se;
  const int tid = threadIdx.x;
  const int lr = tid >> 4;
  const int lc = (tid & 15) * 4;
#pragma unroll
  for (int r = 0; r < 4; ++r) {
    const int e = lr + r * 16;
    const float2 st = stb[e0 + e];
    half4v v = *(const half4v*)(Sb + (size_t)(e0 + e) * St + t0 + lc);
#pragma unroll
    for (int j = 0; j < 4; ++j) {
      const float pv = __expf((float)v[j] - st.x) * st.y;
      tile[lc + j][e] = (_Float16)pv;
    }
  }
  __syncthreads();
#pragma unroll
  for (int r = 0; r < 4; ++r) {
    const int t = lr + r * 16;
    half4v w;
#pragma unroll
    for (int j = 0; j < 4; ++j) w[j] = tile[t][lc + j];
    *(half4v*)(Pb + (size_t)(t0 + t) * Se + e0 + lc) = w;
  }
}

// ---------------------------------------------------------------------------
extern "C" void kernel_launch(void* const* d_in, const int* in_sizes, int n_in,
                              void* d_out, int out_size, void* d_ws,
                              size_t ws_size, hipStream_t stream) {
  const float* enc = (const float*)d_in[0];
  const float* dec = (const float*)d_in[1];
  float* out = (float*)d_out;

  const int B = 8, SE = 2048, SD = 2048, D = 1024;
  char* ws = (char*)d_ws;
  _Float16* enc_h = (_Float16*)ws;                        // 32 MiB
  _Float16* dec_h = (_Float16*)(ws + 33554432);           // 32 MiB
  _Float16* PT = (_Float16*)ws;                           // 64 MiB (reuse)
  _Float16* enc_hT = (_Float16*)(ws + 67108864);          // 32 MiB
  _Float16* S_h = (_Float16*)(ws + 100663296);            // 64 MiB
  float2* stats = (float2*)(ws + 167772160);              // 128 KiB

  // 1. enc convert (+transpose)
  conv_enc<<<dim3(D / 64, SE / 64, B), 256, 0, stream>>>(enc, enc_h, enc_hT,
                                                         SE, D);
  // 2. dec convert
  conv_dec<<<dim3((size_t)B * SD * D / 1024), 256, 0, stream>>>(dec, dec_h);
  // 3. S = enc_h @ dec_h^T  (M=SE, N=SD, K=D)
  gemm_bt<_Float16><<<dim3(SD / BN, SE / BM, B), 256, 0, stream>>>(
      enc_h, dec_h, S_h, D, (long)SE * D, (long)SD * D, (long)SE * SD, D, D,
      SD);
  // 4. row stats
  row_stats<<<dim3(B * SE), 256, 0, stream>>>(S_h, stats);
  // 5. PT[t][e] = exp(S-m)*rl
  norm_transpose<<<dim3(SD / 64, SE / 64, B), 256, 0, stream>>>(S_h, stats, PT,
                                                                SE, SD);
  // 6. out[t][d] = sum_e PT[t][e] * enc_hT[d][e]  (M=SD, N=D, K=SE)
  gemm_bt<float><<<dim3(D / BN, SD / BM, B), 256, 0, stream>>>(
      PT, enc_hT, out, SE, (long)SD * SE, (long)D * SE, (long)SD * D, SE, SE,
      D);
}

// Round 2
// 376.205 us; speedup vs baseline: 1.0520x; 1.0520x over previous
//
#include <hip/hip_runtime.h>

// ---------------------------------------------------------------------------
// Attention_20117626815094: c_t[b,t,d] = sum_e softmax_t(enc@dec^T)[e,t] * enc[e,d]
//   B=8, S_ENC=2048, S_DEC=2048, D=1024, fp32 in/out. f16 MFMA compute.
// Pipeline:
//   1. conv_enc:  enc fp32 -> enc_h [e][d] f16 AND enc_hT [d][e] f16
//   2. conv_dec:  dec fp32 -> dec_h [t][d] f16
//   3. gemm1:     S_h[e][t] = enc_h @ dec_h^T      (32x32x16 MFMA, f16 out)
//   4. row_stats: per (b,e) row: m = max_t S, rl = 1/sum exp(S-m)
//   5. norm_T:    PT[t][e] = exp(S[e][t]-m_e)*rl_e (reg micro-transpose)
//   6. gemm2:     out[t][d] = PT @ enc_hT^T-form   (fp32 out)
// ---------------------------------------------------------------------------

typedef _Float16 half8 __attribute__((ext_vector_type(8)));
typedef _Float16 half4v __attribute__((ext_vector_type(4)));
typedef float floatx16 __attribute__((ext_vector_type(16)));

#define BM 128
#define BN 128
#define BK 32

__device__ __forceinline__ void async_load16(const _Float16* g, void* l) {
  __builtin_amdgcn_global_load_lds(
      (const __attribute__((address_space(1))) void*)g,
      (__attribute__((address_space(3))) void*)l, 16, 0, 0);
}

// ---- GEMM: C[m][n] = sum_k A[m][k] * Bt[n][k]; A,Bt row-major f16 ---------
// 32x32x16_f16 MFMA, XOR-swizzled LDS chunks, XCD-aware block swizzle.
// RN: n-tiles per XCD region (grid must be gx=2*RN, gy=16).
template <typename OutT, int RN>
__global__ __launch_bounds__(256, 2) void gemm_bt(
    const _Float16* __restrict__ A, const _Float16* __restrict__ Bt,
    OutT* __restrict__ C, int K, long strideA, long strideB, long strideC,
    int ldA, int ldB, int ldC) {
  __shared__ _Float16 lds_a[BM * BK];
  __shared__ _Float16 lds_b[BN * BK];

  const int b = blockIdx.z;
  A += (long)b * strideA;
  Bt += (long)b * strideB;
  C += (long)b * strideC;

  // XCD-aware swizzle: blocks with id%8 == x form a compact 4(m) x RN(n) region
  const int id = blockIdx.y * gridDim.x + blockIdx.x;
  const int xcd = id & 7;
  const int l = id >> 3;
  const int by = (xcd & 3) * 4 + l / RN;
  const int bx = (xcd >> 2) * RN + l % RN;
  const int m0 = by * BM;
  const int n0 = bx * BN;

  const int tid = threadIdx.x;
  const int lane = tid & 63;
  const int wave = tid >> 6;
  const int l31 = lane & 31;
  const int kh = lane >> 5;  // k-half for 32x32x16 fragments
  const int wm = (wave >> 1) * 64;
  const int wn = (wave & 1) * 64;

  floatx16 acc[2][2] = {};

  for (int k0 = 0; k0 < K; k0 += BK) {
    // stage A (8KB) and B (8KB): 2 async 16B chunks per thread per tile.
    // physical LDS slot is fixed (base+lane*16); we XOR-swizzle WHICH global
    // 16B chunk goes there: phys chunk c holds logical chunk c^(row&3).
#pragma unroll
    for (int c = 0; c < 2; ++c) {
      const int off = c * 4096 + wave * 1024 + lane * 16;  // bytes in tile
      const int row = off >> 6;                            // 64B per row
      const int ke = (((off >> 4) & 3) ^ (row & 3)) * 8;   // f16 elems in row
      async_load16(A + (long)(m0 + row) * ldA + k0 + ke, (char*)lds_a + off);
      async_load16(Bt + (long)(n0 + row) * ldB + k0 + ke, (char*)lds_b + off);
    }
    __syncthreads();

    half8 af[2][2], bf[2][2];
#pragma unroll
    for (int i = 0; i < 2; ++i) {
      const int ra = wm + i * 32 + l31;
      const int rb = wn + i * 32 + l31;
#pragma unroll
      for (int s = 0; s < 2; ++s) {
        const int ck = s * 2 + kh;  // logical 16B chunk within row
        af[i][s] = *(const half8*)((const char*)lds_a + ra * 64 +
                                   ((ck ^ (ra & 3)) << 4));
        bf[i][s] = *(const half8*)((const char*)lds_b + rb * 64 +
                                   ((ck ^ (rb & 3)) << 4));
      }
    }
#pragma unroll
    for (int s = 0; s < 2; ++s)
#pragma unroll
      for (int i = 0; i < 2; ++i)
#pragma unroll
        for (int j = 0; j < 2; ++j)
          acc[i][j] = __builtin_amdgcn_mfma_f32_32x32x16_f16(
              af[i][s], bf[j][s], acc[i][j], 0, 0, 0);
    __syncthreads();
  }

  // C/D layout (measured): col=lane&31, row=(reg&3)+8*(reg>>2)+4*(lane>>5)
#pragma unroll
  for (int i = 0; i < 2; ++i) {
    const int r_base = m0 + wm + i * 32 + 4 * kh;
#pragma unroll
    for (int j = 0; j < 2; ++j) {
      const int col = n0 + wn + j * 32 + l31;
#pragma unroll
      for (int g = 0; g < 4; ++g)
#pragma unroll
        for (int rr = 0; rr < 4; ++rr)
          C[(long)(r_base + g * 8 + rr) * ldC + col] =
              (OutT)acc[i][j][g * 4 + rr];
    }
  }
}

// ---- enc convert + transpose (4x4 register micro-transpose) ---------------
__global__ __launch_bounds__(256) void conv_enc(const float* __restrict__ E,
                                                _Float16* __restrict__ Eh,
                                                _Float16* __restrict__ EhT,
                                                int Se, int D) {
  __shared__ _Float16 T[64][72];  // [d_local][e_local]; 72*2=144B rows, 16B-mult
  const int b = blockIdx.z;
  const int d0 = blockIdx.x * 64;
  const int e0 = blockIdx.y * 64;
  const float* Eb = E + (size_t)b * Se * D;
  _Float16* Ehb = Eh + (size_t)b * Se * D;
  _Float16* EhTb = EhT + (size_t)b * D * Se;
  const int tid = threadIdx.x;
  const int tx = tid & 15;   // d chunk (4 floats)
  const int ty = tid >> 4;   // e chunk (4 rows)

  half4v h[4];
#pragma unroll
  for (int r = 0; r < 4; ++r) {
    const int e = e0 + ty * 4 + r;
    float4 v = *(const float4*)(Eb + (size_t)e * D + d0 + tx * 4);
    h[r][0] = (_Float16)v.x; h[r][1] = (_Float16)v.y;
    h[r][2] = (_Float16)v.z; h[r][3] = (_Float16)v.w;
    *(half4v*)(Ehb + (size_t)e * D + d0 + tx * 4) = h[r];
  }
#pragma unroll
  for (int c = 0; c < 4; ++c) {
    half4v w;
#pragma unroll
    for (int r = 0; r < 4; ++r) w[r] = h[r][c];
    *(half4v*)&T[tx * 4 + c][ty * 4] = w;  // 8B LDS write, transposed pos
  }
  __syncthreads();
#pragma unroll
  for (int p = 0; p < 2; ++p) {
    const int idx = tid + p * 256;
    const int row = idx >> 3;    // d_local
    const int ck = idx & 7;      // 8-elem chunk along e
    *(half8*)(EhTb + (size_t)(d0 + row) * Se + e0 + ck * 8) =
        *(const half8*)&T[row][ck * 8];  // 16B coalesced store
  }
}

// ---- dec convert (16B stores) ---------------------------------------------
__global__ __launch_bounds__(256) void conv_dec(const float* __restrict__ X,
                                                _Float16* __restrict__ Y) {
  const size_t i = ((size_t)blockIdx.x * 256 + threadIdx.x) * 8;
  float4 a = *(const float4*)(X + i);
  float4 b = *(const float4*)(X + i + 4);
  half8 h;
  h[0] = (_Float16)a.x; h[1] = (_Float16)a.y;
  h[2] = (_Float16)a.z; h[3] = (_Float16)a.w;
  h[4] = (_Float16)b.x; h[5] = (_Float16)b.y;
  h[6] = (_Float16)b.z; h[7] = (_Float16)b.w;
  *(half8*)(Y + i) = h;
}

// ---- per-row softmax stats: one wave per row, shuffle-only ----------------
__global__ __launch_bounds__(256) void row_stats(const _Float16* __restrict__ S,
                                                 float2* __restrict__ stats) {
  const int lane = threadIdx.x & 63;
  const long row = (long)blockIdx.x * 4 + (threadIdx.x >> 6);
  const _Float16* p = S + row * 2048;

  float f[32];
#pragma unroll
  for (int q = 0; q < 4; ++q) {
    half8 v = *(const half8*)(p + q * 512 + lane * 8);
#pragma unroll
    for (int j = 0; j < 8; ++j) f[q * 8 + j] = (float)v[j];
  }
  float mx = f[0];
#pragma unroll
  for (int j = 1; j < 32; ++j) mx = fmaxf(mx, f[j]);
  for (int o = 32; o; o >>= 1) mx = fmaxf(mx, __shfl_xor(mx, o, 64));
  float s = 0.f;
#pragma unroll
  for (int j = 0; j < 32; ++j) s += __expf(f[j] - mx);
  for (int o = 32; o; o >>= 1) s += __shfl_xor(s, o, 64);
  if (lane == 0) stats[row] = make_float2(mx, 1.0f / s);
}

// ---- normalize + transpose: PT[t][e] = exp(S[e][t]-m_e)*rl_e --------------
__global__ __launch_bounds__(256) void norm_transpose(
    const _Float16* __restrict__ S, const float2* __restrict__ stats,
    _Float16* __restrict__ PT, int Se, int St) {
  __shared__ _Float16 T[64][72];  // [t_local][e_local]
  const int b = blockIdx.z;
  const int t0 = blockIdx.x * 64;
  const int e0 = blockIdx.y * 64;
  const _Float16* Sb = S + (size_t)b * Se * St;
  _Float16* Pb = PT + (size_t)b * St * Se;
  const float2* stb = stats + (size_t)b * Se;
  const int tid = threadIdx.x;
  const int tx = tid & 15;   // t chunk (4 cols)
  const int ty = tid >> 4;   // e chunk (4 rows)

  half4v pr[4];
#pragma unroll
  for (int r = 0; r < 4; ++r) {
    const int e = e0 + ty * 4 + r;
    const float2 st = stb[e];
    half4v v = *(const half4v*)(Sb + (size_t)e * St + t0 + tx * 4);
#pragma unroll
    for (int c = 0; c < 4; ++c)
      pr[r][c] = (_Float16)(__expf((float)v[c] - st.x) * st.y);
  }
#pragma unroll
  for (int c = 0; c < 4; ++c) {
    half4v w;
#pragma unroll
    for (int r = 0; r < 4; ++r) w[r] = pr[r][c];
    *(half4v*)&T[tx * 4 + c][ty * 4] = w;
  }
  __syncthreads();
#pragma unroll
  for (int p = 0; p < 2; ++p) {
    const int idx = tid + p * 256;
    const int row = idx >> 3;   // t_local
    const int ck = idx & 7;     // e chunk
    *(half8*)(Pb + (size_t)(t0 + row) * Se + e0 + ck * 8) =
        *(const half8*)&T[row][ck * 8];
  }
}

// ---------------------------------------------------------------------------
extern "C" void kernel_launch(void* const* d_in, const int* in_sizes, int n_in,
                              void* d_out, int out_size, void* d_ws,
                              size_t ws_size, hipStream_t stream) {
  const float* enc = (const float*)d_in[0];
  const float* dec = (const float*)d_in[1];
  float* out = (float*)d_out;

  const int B = 8, SE = 2048, SD = 2048, D = 1024;
  char* ws = (char*)d_ws;
  _Float16* enc_h = (_Float16*)ws;                        // 32 MiB
  _Float16* dec_h = (_Float16*)(ws + 33554432);           // 32 MiB
  _Float16* PT = (_Float16*)ws;                           // 64 MiB (reuse)
  _Float16* enc_hT = (_Float16*)(ws + 67108864);          // 32 MiB
  _Float16* S_h = (_Float16*)(ws + 100663296);            // 64 MiB
  float2* stats = (float2*)(ws + 167772160);              // 128 KiB

  conv_enc<<<dim3(D / 64, SE / 64, B), 256, 0, stream>>>(enc, enc_h, enc_hT,
                                                         SE, D);
  conv_dec<<<dim3((size_t)B * SD * D / 2048), 256, 0, stream>>>(dec, dec_h);
  // S = enc_h @ dec_h^T  (M=SE, N=SD, K=D); grid gx=16 -> RN=8
  gemm_bt<_Float16, 8><<<dim3(SD / BN, SE / BM, B), 256, 0, stream>>>(
      enc_h, dec_h, S_h, D, (long)SE * D, (long)SD * D, (long)SE * SD, D, D,
      SD);
  row_stats<<<dim3(B * SE / 4), 256, 0, stream>>>(S_h, stats);
  norm_transpose<<<dim3(SD / 64, SE / 64, B), 256, 0, stream>>>(S_h, stats, PT,
                                                                SE, SD);
  // out[t][d] = sum_e PT[t][e] * enc_hT[d][e]  (M=SD, N=D, K=SE); gx=8 -> RN=4
  gemm_bt<float, 4><<<dim3(D / BN, SD / BM, B), 256, 0, stream>>>(
      PT, enc_hT, out, SE, (long)SD * SE, (long)D * SE, (long)SD * D, SE, SE,
      D);
}

// Round 3
// 349.945 us; speedup vs baseline: 1.1309x; 1.0750x over previous
//
#include <hip/hip_runtime.h>

// ---------------------------------------------------------------------------
// Attention_20117626815094: c_t[b,t,d] = sum_e softmax_t(enc@dec^T)[e,t] * enc[e,d]
//   B=8, S_ENC=2048, S_DEC=2048, D=1024, fp32 in/out. f16 MFMA compute.
// Pipeline (v3 — transpose-free softmax path):
//   1. conv_enc:  enc fp32 -> enc_h [e][d] f16 AND enc_hT [d][e] f16
//   2. conv_dec:  dec fp32 -> dec_h [t][d] f16
//   3. gemm1:     ST[t][e] = (enc_h @ dec_h^T)^T   (LDS-transposed epilogue)
//   4. col_stats: online softmax over t per (b,e) column -> partials
//   5. stats_combine: merge t-chunk partials -> stats[b][e] = (m, 1/sum)
//   6. norm_stream: P[t][e] = exp(ST-m_e)*rl_e     (pure stream, no LDS)
//   7. gemm2:     out[t][d] = P @ enc_hT^T-form    (fp32 out)
// ---------------------------------------------------------------------------

typedef _Float16 half8 __attribute__((ext_vector_type(8)));
typedef _Float16 half4v __attribute__((ext_vector_type(4)));
typedef float floatx16 __attribute__((ext_vector_type(16)));

#define BM 128
#define BN 128
#define BK 64

__device__ __forceinline__ void async_load16(const _Float16* g, void* l) {
  __builtin_amdgcn_global_load_lds(
      (const __attribute__((address_space(1))) void*)g,
      (__attribute__((address_space(3))) void*)l, 16, 0, 0);
}

// ---- GEMM: C = A @ Bt^T; A,Bt row-major f16, k contiguous -----------------
// TRANS=true: write C^T (f16) via LDS transpose, ldC = row stride of C^T.
template <typename OutT, bool TRANS, int RN>
__global__ __launch_bounds__(256, 2) void gemm_bt(
    const _Float16* __restrict__ A, const _Float16* __restrict__ Bt,
    OutT* __restrict__ C, int K, long strideA, long strideB, long strideC,
    int ldA, int ldB, int ldC) {
  constexpr int CPR = BK / 8;   // 16B chunks per LDS row
  constexpr int SK = BK / 16;   // mfma k-substeps per tile
  __shared__ alignas(16) char smem[TRANS ? (128 * 136 * 2) : (2 * BM * BK * 2)];
  _Float16* lds_a = (_Float16*)smem;
  _Float16* lds_b = (_Float16*)(smem + BM * BK * 2);

  const int b = blockIdx.z;
  A += (long)b * strideA;
  Bt += (long)b * strideB;
  C += (long)b * strideC;

  // XCD-aware swizzle: blocks with id%8==x form a compact 4(m) x RN(n) region
  const int id = blockIdx.y * gridDim.x + blockIdx.x;
  const int xcd = id & 7;
  const int l = id >> 3;
  const int m0 = ((xcd & 3) * 4 + l / RN) * BM;
  const int n0 = ((xcd >> 2) * RN + l % RN) * BN;

  const int tid = threadIdx.x;
  const int lane = tid & 63;
  const int wave = tid >> 6;
  const int l31 = lane & 31;
  const int kh = lane >> 5;
  const int wm = (wave >> 1) * 64;
  const int wn = (wave & 1) * 64;

  floatx16 acc[2][2] = {};

  for (int k0 = 0; k0 < K; k0 += BK) {
    // stage A,B tiles (16KB each): 4 async 16B chunks per thread per tile.
    // XOR-swizzle which global chunk lands in each fixed LDS slot.
#pragma unroll
    for (int c = 0; c < 4; ++c) {
      const int off = c * 4096 + wave * 1024 + lane * 16;  // bytes in tile
      const int row = off >> 7;                            // 128B per row
      const int ke = (((off >> 4) & (CPR - 1)) ^ (row & (CPR - 1))) * 8;
      async_load16(A + (long)(m0 + row) * ldA + k0 + ke, (char*)lds_a + off);
      async_load16(Bt + (long)(n0 + row) * ldB + k0 + ke, (char*)lds_b + off);
    }
    __syncthreads();

    half8 af[2][SK], bf[2][SK];
#pragma unroll
    for (int i = 0; i < 2; ++i) {
      const int ra = wm + i * 32 + l31;
      const int rb = wn + i * 32 + l31;
#pragma unroll
      for (int s = 0; s < SK; ++s) {
        const int ck = s * 2 + kh;  // logical 16B chunk (k = ck*8 + j)
        af[i][s] = *(const half8*)((const char*)lds_a + ra * (BK * 2) +
                                   ((ck ^ (ra & (CPR - 1))) << 4));
        bf[i][s] = *(const half8*)((const char*)lds_b + rb * (BK * 2) +
                                   ((ck ^ (rb & (CPR - 1))) << 4));
      }
    }
#pragma unroll
    for (int s = 0; s < SK; ++s)
#pragma unroll
      for (int i = 0; i < 2; ++i)
#pragma unroll
        for (int j = 0; j < 2; ++j)
          acc[i][j] = __builtin_amdgcn_mfma_f32_32x32x16_f16(
              af[i][s], bf[j][s], acc[i][j], 0, 0, 0);
    __syncthreads();
  }

  // C/D layout (verified): col=lane&31, row=(reg&3)+8*(reg>>2)+4*(lane>>5)
  if constexpr (TRANS) {
    // write C^T[n][m] (f16): regs rr=0..3 are m-consecutive -> 8B LDS writes
    _Float16(*TT)[136] = (_Float16(*)[136])smem;
#pragma unroll
    for (int i = 0; i < 2; ++i)
#pragma unroll
      for (int j = 0; j < 2; ++j) {
        const int tl = wn + j * 32 + l31;
#pragma unroll
        for (int g = 0; g < 4; ++g) {
          half4v h;
#pragma unroll
          for (int rr = 0; rr < 4; ++rr) h[rr] = (_Float16)acc[i][j][g * 4 + rr];
          *(half4v*)&TT[tl][wm + i * 32 + 4 * kh + g * 8] = h;
        }
      }
    __syncthreads();
#pragma unroll
    for (int p = 0; p < 8; ++p) {
      const int idx = p * 256 + tid;
      const int tl = idx >> 4;
      const int ck = idx & 15;
      *(half8*)((_Float16*)C + (long)(n0 + tl) * ldC + m0 + ck * 8) =
          *(const half8*)&TT[tl][ck * 8];
    }
  } else {
#pragma unroll
    for (int i = 0; i < 2; ++i) {
      const int r_base = m0 + wm + i * 32 + 4 * kh;
#pragma unroll
      for (int j = 0; j < 2; ++j) {
        const int col = n0 + wn + j * 32 + l31;
#pragma unroll
        for (int g = 0; g < 4; ++g)
#pragma unroll
          for (int rr = 0; rr < 4; ++rr)
            C[(long)(r_base + g * 8 + rr) * ldC + col] =
                (OutT)acc[i][j][g * 4 + rr];
      }
    }
  }
}

// ---- enc convert + transpose (4x4 register micro-transpose) ---------------
__global__ __launch_bounds__(256) void conv_enc(const float* __restrict__ E,
                                                _Float16* __restrict__ Eh,
                                                _Float16* __restrict__ EhT,
                                                int Se, int D) {
  __shared__ _Float16 T[64][72];
  const int b = blockIdx.z;
  const int d0 = blockIdx.x * 64;
  const int e0 = blockIdx.y * 64;
  const float* Eb = E + (size_t)b * Se * D;
  _Float16* Ehb = Eh + (size_t)b * Se * D;
  _Float16* EhTb = EhT + (size_t)b * D * Se;
  const int tid = threadIdx.x;
  const int tx = tid & 15;
  const int ty = tid >> 4;

  half4v h[4];
#pragma unroll
  for (int r = 0; r < 4; ++r) {
    const int e = e0 + ty * 4 + r;
    float4 v = *(const float4*)(Eb + (size_t)e * D + d0 + tx * 4);
    h[r][0] = (_Float16)v.x; h[r][1] = (_Float16)v.y;
    h[r][2] = (_Float16)v.z; h[r][3] = (_Float16)v.w;
    *(half4v*)(Ehb + (size_t)e * D + d0 + tx * 4) = h[r];
  }
#pragma unroll
  for (int c = 0; c < 4; ++c) {
    half4v w;
#pragma unroll
    for (int r = 0; r < 4; ++r) w[r] = h[r][c];
    *(half4v*)&T[tx * 4 + c][ty * 4] = w;
  }
  __syncthreads();
#pragma unroll
  for (int p = 0; p < 2; ++p) {
    const int idx = tid + p * 256;
    const int row = idx >> 3;
    const int ck = idx & 7;
    *(half8*)(EhTb + (size_t)(d0 + row) * Se + e0 + ck * 8) =
        *(const half8*)&T[row][ck * 8];
  }
}

// ---- dec convert (16B stores) ---------------------------------------------
__global__ __launch_bounds__(256) void conv_dec(const float* __restrict__ X,
                                                _Float16* __restrict__ Y) {
  const size_t i = ((size_t)blockIdx.x * 256 + threadIdx.x) * 8;
  float4 a = *(const float4*)(X + i);
  float4 b = *(const float4*)(X + i + 4);
  half8 h;
  h[0] = (_Float16)a.x; h[1] = (_Float16)a.y;
  h[2] = (_Float16)a.z; h[3] = (_Float16)a.w;
  h[4] = (_Float16)b.x; h[5] = (_Float16)b.y;
  h[6] = (_Float16)b.z; h[7] = (_Float16)b.w;
  *(half8*)(Y + i) = h;
}

// ---- column-wise online softmax stats over ST[t][e] -----------------------
// grid: (e_chunks=32, t_chunks=4, B); block 256. Each block: 64 e x 512 t.
__global__ __launch_bounds__(256) void col_stats(const _Float16* __restrict__ ST,
                                                 float2* __restrict__ part) {
  __shared__ float2 red[16][65];
  const int b = blockIdx.z;
  const int e0 = blockIdx.x * 64;
  const int t0 = blockIdx.y * 512;
  const _Float16* S = ST + (size_t)b * 2048 * 2048;
  const int tx = threadIdx.x & 15;
  const int ty = threadIdx.x >> 4;

  float m[4] = {-1e30f, -1e30f, -1e30f, -1e30f};
  float s[4] = {0.f, 0.f, 0.f, 0.f};
  for (int it = 0; it < 32; ++it) {
    const int t = t0 + it * 16 + ty;
    half4v v = *(const half4v*)(S + (size_t)t * 2048 + e0 + tx * 4);
#pragma unroll
    for (int c = 0; c < 4; ++c) {
      const float x = (float)v[c];
      const float m2 = fmaxf(m[c], x);
      s[c] = s[c] * __expf(m[c] - m2) + __expf(x - m2);
      m[c] = m2;
    }
  }
#pragma unroll
  for (int c = 0; c < 4; ++c) red[ty][tx * 4 + c] = make_float2(m[c], s[c]);
  __syncthreads();
  if (threadIdx.x < 64) {
    float2 a = red[0][threadIdx.x];
#pragma unroll
    for (int r = 1; r < 16; ++r) {
      const float2 o = red[r][threadIdx.x];
      const float m2 = fmaxf(a.x, o.x);
      a.y = a.y * __expf(a.x - m2) + o.y * __expf(o.x - m2);
      a.x = m2;
    }
    part[(size_t)blockIdx.y * 16384 + (size_t)b * 2048 + e0 + threadIdx.x] = a;
  }
}

// ---- merge 4 t-chunk partials -> stats = (m, 1/sum) -----------------------
__global__ __launch_bounds__(256) void stats_combine(
    const float2* __restrict__ part, float2* __restrict__ stats) {
  const int idx = blockIdx.x * 256 + threadIdx.x;  // b*2048+e
  float2 a = part[idx];
#pragma unroll
  for (int tc = 1; tc < 4; ++tc) {
    const float2 o = part[tc * 16384 + idx];
    const float m2 = fmaxf(a.x, o.x);
    a.y = a.y * __expf(a.x - m2) + o.y * __expf(o.x - m2);
    a.x = m2;
  }
  stats[idx] = make_float2(a.x, 1.0f / a.y);
}

// ---- streaming normalize: P[t][e] = exp(ST-m_e)*rl_e ----------------------
// grid: (512, 8); block 256; 4 t-rows per block, stats reused across rows.
__global__ __launch_bounds__(256) void norm_stream(
    const _Float16* __restrict__ ST, const float2* __restrict__ stats,
    _Float16* __restrict__ P) {
  const int b = blockIdx.y;
  const int t0 = blockIdx.x * 4;
  const int e = threadIdx.x * 8;
  float m_[8], rl_[8];
#pragma unroll
  for (int j = 0; j < 8; ++j) {
    const float2 st = stats[(size_t)b * 2048 + e + j];
    m_[j] = st.x;
    rl_[j] = st.y;
  }
  const size_t base = ((size_t)b * 2048 + t0) * 2048 + e;
#pragma unroll
  for (int r = 0; r < 4; ++r) {
    half8 v = *(const half8*)(ST + base + (size_t)r * 2048);
    half8 o;
#pragma unroll
    for (int j = 0; j < 8; ++j)
      o[j] = (_Float16)(__expf((float)v[j] - m_[j]) * rl_[j]);
    *(half8*)(P + base + (size_t)r * 2048) = o;
  }
}

// ---------------------------------------------------------------------------
extern "C" void kernel_launch(void* const* d_in, const int* in_sizes, int n_in,
                              void* d_out, int out_size, void* d_ws,
                              size_t ws_size, hipStream_t stream) {
  const float* enc = (const float*)d_in[0];
  const float* dec = (const float*)d_in[1];
  float* out = (float*)d_out;

  const int B = 8, SE = 2048, SD = 2048, D = 1024;
  char* ws = (char*)d_ws;
  _Float16* enc_h = (_Float16*)ws;                 // 32 MiB (dead after gemm1)
  _Float16* dec_h = (_Float16*)(ws + 33554432);    // 32 MiB (dead after gemm1)
  _Float16* P = (_Float16*)ws;                     // 64 MiB (reuses enc/dec_h)
  _Float16* enc_hT = (_Float16*)(ws + 67108864);   // 32 MiB
  _Float16* ST = (_Float16*)(ws + 100663296);      // 64 MiB
  float2* stats = (float2*)(ws + 167772160);       // 128 KiB
  float2* part = (float2*)(ws + 167903232);        // 512 KiB

  conv_enc<<<dim3(D / 64, SE / 64, B), 256, 0, stream>>>(enc, enc_h, enc_hT,
                                                         SE, D);
  conv_dec<<<dim3((size_t)B * SD * D / 2048), 256, 0, stream>>>(dec, dec_h);
  // ST[t][e] = (enc_h @ dec_h^T)^T  (M=e, N=t, K=D); gx=16 -> RN=8
  gemm_bt<_Float16, true, 8><<<dim3(SD / BN, SE / BM, B), 256, 0, stream>>>(
      enc_h, dec_h, ST, D, (long)SE * D, (long)SD * D, (long)SE * SD, D, D,
      SE);
  col_stats<<<dim3(32, 4, B), 256, 0, stream>>>(ST, part);
  stats_combine<<<dim3(64), 256, 0, stream>>>(part, stats);
  norm_stream<<<dim3(512, B), 256, 0, stream>>>(ST, stats, P);
  // out[t][d] = P @ enc_hT^T-form  (M=t, N=d, K=e); gx=8 -> RN=4
  gemm_bt<float, false, 4><<<dim3(D / BN, SD / BM, B), 256, 0, stream>>>(
      P, enc_hT, out, SE, (long)SD * SE, (long)D * SE, (long)SD * D, SE, SE,
      D);
}